// Round 5
// baseline (600.181 us; speedup 1.0000x reference)
//
#include <hip/hip_runtime.h>

// VQ-VAE VectorQuantizer: x[32768,256] fp32, emb[256,1024] fp32.
// Round 5: bf16-MFMA screen (unchanged, verified r4) + restructured rescue:
//   - up to 4 flagged groups handled per 256-fmaf chain pass (lane-groups)
//   - emb columns streamed from embT (per-lane contiguous float4)
//   - merge (gather + out write + loss) fused into the rescue wave
// Flag set and all rounding bit-identical to the r4 passing run.

#define D 256
#define K 1024
#define N_PTS 32768

typedef __attribute__((ext_vector_type(8))) short short8v;   // 8 bf16 (4 VGPR)
typedef __attribute__((ext_vector_type(4))) float f32x4;     // MFMA acc
typedef __attribute__((ext_vector_type(4))) unsigned short us4v;

__device__ __forceinline__ unsigned short bf16rne(float f) {
    unsigned u = __float_as_uint(f);                 // finite data, no NaN
    return (unsigned short)((u + 0x7FFFu + ((u >> 16) & 1u)) >> 16);
}

// ws layout (bytes):
//   0        float  enorm[1024]        4 KB   (numpy-sequential fp32 ||e||^2)
//   8192     double lossacc            8 B
//   16384    float  Anorm[32768]       128 KB (numpy pairwise ||x||^2)
//   147456   float  Sabs[32768]        128 KB (sum|x| for margin bound)
//   409600   ushort ehT[1024][256]     512 KB (bf16, code-major)
//   933888   float  embT[1024][256]    1 MB   (f32, code-major)
//   1982464  float  gmin16[32768][64]  8 MB
// xh bf16 [32768][256] (16 MB) lives in d_out scratch (consumed by screen,
// overwritten by the fused rescue/merge afterwards).

__global__ __launch_bounds__(256) void vq_prepx(const float* __restrict__ x,
                                                float* __restrict__ Anorm,
                                                float* __restrict__ Sabs,
                                                unsigned short* __restrict__ xh) {
    const int tid = threadIdx.x;
    const int gt  = blockIdx.x * 256 + tid;
    const int n   = gt >> 1;
    const int h   = gt & 1;            // lane pair (2j,2j+1) = halves of row n
    const float4* __restrict__ xr =
        reinterpret_cast<const float4*>(x + (size_t)n * D) + h * 32;
    unsigned short* __restrict__ xo = xh + (size_t)n * D + h * 128;

    // numpy pairwise fp32 half-block: 8 accumulators, strided adds,
    // combine ((r0+r1)+(r2+r3))+((r4+r5)+(r6+r7))
    float r[8], sab;
    float4 u = xr[0], v = xr[1];
    {
        short8v p;
        p[0]=(short)bf16rne(u.x); p[1]=(short)bf16rne(u.y);
        p[2]=(short)bf16rne(u.z); p[3]=(short)bf16rne(u.w);
        p[4]=(short)bf16rne(v.x); p[5]=(short)bf16rne(v.y);
        p[6]=(short)bf16rne(v.z); p[7]=(short)bf16rne(v.w);
        *reinterpret_cast<short8v*>(xo) = p;
    }
    r[0]=__fmul_rn(u.x,u.x); r[1]=__fmul_rn(u.y,u.y);
    r[2]=__fmul_rn(u.z,u.z); r[3]=__fmul_rn(u.w,u.w);
    r[4]=__fmul_rn(v.x,v.x); r[5]=__fmul_rn(v.y,v.y);
    r[6]=__fmul_rn(v.z,v.z); r[7]=__fmul_rn(v.w,v.w);
    sab = fabsf(u.x)+fabsf(u.y)+fabsf(u.z)+fabsf(u.w)
        + fabsf(v.x)+fabsf(v.y)+fabsf(v.z)+fabsf(v.w);
    #pragma unroll
    for (int i = 1; i < 16; ++i) {
        u = xr[2*i]; v = xr[2*i+1];
        short8v p;
        p[0]=(short)bf16rne(u.x); p[1]=(short)bf16rne(u.y);
        p[2]=(short)bf16rne(u.z); p[3]=(short)bf16rne(u.w);
        p[4]=(short)bf16rne(v.x); p[5]=(short)bf16rne(v.y);
        p[6]=(short)bf16rne(v.z); p[7]=(short)bf16rne(v.w);
        *reinterpret_cast<short8v*>(xo + i * 8) = p;
        r[0]=__fadd_rn(r[0],__fmul_rn(u.x,u.x));
        r[1]=__fadd_rn(r[1],__fmul_rn(u.y,u.y));
        r[2]=__fadd_rn(r[2],__fmul_rn(u.z,u.z));
        r[3]=__fadd_rn(r[3],__fmul_rn(u.w,u.w));
        r[4]=__fadd_rn(r[4],__fmul_rn(v.x,v.x));
        r[5]=__fadd_rn(r[5],__fmul_rn(v.y,v.y));
        r[6]=__fadd_rn(r[6],__fmul_rn(v.z,v.z));
        r[7]=__fadd_rn(r[7],__fmul_rn(v.w,v.w));
        sab += fabsf(u.x)+fabsf(u.y)+fabsf(u.z)+fabsf(u.w)
             + fabsf(v.x)+fabsf(v.y)+fabsf(v.z)+fabsf(v.w);
    }
    float ah = __fadd_rn(__fadd_rn(__fadd_rn(r[0],r[1]),__fadd_rn(r[2],r[3])),
                         __fadd_rn(__fadd_rn(r[4],r[5]),__fadd_rn(r[6],r[7])));
    float oh = __shfl_xor(ah, 1);
    float os = __shfl_xor(sab, 1);
    if (h == 0) {
        Anorm[n] = __fadd_rn(ah, oh);   // fl(half0 + half1), numpy order
        Sabs[n]  = sab + os;
    }
}

__global__ __launch_bounds__(256) void vq_enorm(const float* __restrict__ emb,
                                                float* __restrict__ enorm) {
    int k = blockIdx.x * 256 + threadIdx.x;
    float c = 0.0f;   // numpy axis-0 sum: sequential over d, square rounded first
    for (int d = 0; d < D; ++d) {
        float e = emb[d * K + k];
        c = __fadd_rn(c, __fmul_rn(e, e));
    }
    enorm[k] = c;
}

// emb transpose: embT[k][d] f32 (rescue/merge) + ehT[k][d] bf16 (screen B)
__global__ __launch_bounds__(256) void vq_prepe(const float* __restrict__ emb,
                                                float* __restrict__ embT,
                                                unsigned short* __restrict__ ehT) {
    __shared__ float tile[64][68];
    const int bk = blockIdx.x >> 2, bd = blockIdx.x & 3;
    const int k0 = bk * 64, d0 = bd * 64;
    const int t = threadIdx.x;
    #pragma unroll
    for (int s = 0; s < 4; ++s) {
        int li = s * 256 + t;
        int dd = li >> 4, kq = li & 15;
        float4 v = *reinterpret_cast<const float4*>(&emb[(size_t)(d0 + dd) * K + k0 + kq * 4]);
        tile[dd][kq*4+0]=v.x; tile[dd][kq*4+1]=v.y;
        tile[dd][kq*4+2]=v.z; tile[dd][kq*4+3]=v.w;
    }
    __syncthreads();
    #pragma unroll
    for (int s = 0; s < 4; ++s) {
        int li = s * 256 + t;
        int kk = li >> 4, dq = li & 15;
        float4 v;
        v.x = tile[dq*4+0][kk]; v.y = tile[dq*4+1][kk];
        v.z = tile[dq*4+2][kk]; v.w = tile[dq*4+3][kk];
        *reinterpret_cast<float4*>(&embT[(size_t)(k0+kk)*D + d0 + dq*4]) = v;
        us4v hq;
        hq[0]=bf16rne(v.x); hq[1]=bf16rne(v.y); hq[2]=bf16rne(v.z); hq[3]=bf16rne(v.w);
        *reinterpret_cast<us4v*>(&ehT[(size_t)(k0+kk)*D + d0 + dq*4]) = hq;
    }
}

// ---- bf16 MFMA screen: 128x128 tile, 4 waves (2x2), 16x16x32 MFMA ----
#define LDSTR 40   // ushorts per LDS row (80B): 16B-aligned, 2-way banks (free)

__global__ __launch_bounds__(256) void vq_screen(const unsigned short* __restrict__ xh,
                                                 const unsigned short* __restrict__ ehT,
                                                 const float* __restrict__ Anorm,
                                                 const float* __restrict__ enorm,
                                                 float* __restrict__ gmin16) {
    __shared__ unsigned short a_lds[128 * LDSTR];
    __shared__ unsigned short b_lds[128 * LDSTR];
    const int tid = threadIdx.x;
    const int l = tid & 63, wid = tid >> 6;
    const int wr = wid >> 1, wc = wid & 1;        // wave tile 64x64
    const int rt = blockIdx.x >> 3, cc = blockIdx.x & 7;
    const int n0 = rt * 128, c0 = cc * 128;
    const int g = l >> 4, cl = l & 15;

    f32x4 acc[4][4];
    #pragma unroll
    for (int mf = 0; mf < 4; ++mf)
        #pragma unroll
        for (int nf = 0; nf < 4; ++nf)
            acc[mf][nf] = (f32x4){0.f, 0.f, 0.f, 0.f};

    const int srow = tid >> 1, sq = (tid & 1) * 2;   // staging: 2x16B per thread
    for (int s = 0; s < 8; ++s) {                    // K = 8 steps of 32
        __syncthreads();
        {
            const short8v* ga = reinterpret_cast<const short8v*>(
                xh + (size_t)(n0 + srow) * D + s * 32 + sq * 8);
            short8v a0 = ga[0], a1 = ga[1];
            *reinterpret_cast<short8v*>(&a_lds[srow * LDSTR + sq * 8])     = a0;
            *reinterpret_cast<short8v*>(&a_lds[srow * LDSTR + sq * 8 + 8]) = a1;
            const short8v* gb = reinterpret_cast<const short8v*>(
                ehT + (size_t)(c0 + srow) * D + s * 32 + sq * 8);
            short8v b0 = gb[0], b1 = gb[1];
            *reinterpret_cast<short8v*>(&b_lds[srow * LDSTR + sq * 8])     = b0;
            *reinterpret_cast<short8v*>(&b_lds[srow * LDSTR + sq * 8 + 8]) = b1;
        }
        __syncthreads();
        short8v af[4], bf[4];
        #pragma unroll
        for (int mf = 0; mf < 4; ++mf)
            af[mf] = *reinterpret_cast<const short8v*>(
                &a_lds[(wr * 64 + mf * 16 + cl) * LDSTR + g * 8]);
        #pragma unroll
        for (int nf = 0; nf < 4; ++nf)
            bf[nf] = *reinterpret_cast<const short8v*>(
                &b_lds[(wc * 64 + nf * 16 + cl) * LDSTR + g * 8]);
        #pragma unroll
        for (int mf = 0; mf < 4; ++mf)
            #pragma unroll
            for (int nf = 0; nf < 4; ++nf)
                acc[mf][nf] = __builtin_amdgcn_mfma_f32_16x16x32_bf16(
                    af[mf], bf[nf], acc[mf][nf], 0, 0, 0);
    }

    // epilogue: screen dist + per-row 16-code group mins
    #pragma unroll
    for (int mf = 0; mf < 4; ++mf) {
        #pragma unroll
        for (int nf = 0; nf < 4; ++nf) {
            f32x4 a = acc[mf][nf];
            const int cg = c0 + wc * 64 + nf * 16 + cl;
            const float C = enorm[cg];
            #pragma unroll
            for (int r = 0; r < 4; ++r) {
                const int ng = n0 + wr * 64 + mf * 16 + g * 4 + r;
                float dist = Anorm[ng] - 2.0f * a[r] + C;
                #pragma unroll
                for (int m = 1; m <= 8; m <<= 1)
                    dist = fminf(dist, __shfl_xor(dist, m));
                if (cl == 0)
                    gmin16[(size_t)ng * 64 + cc * 8 + wc * 4 + nf] = dist;
            }
        }
    }
}

// ---- fused exact rescue + gather/out/loss: one wave per row ----
__global__ __launch_bounds__(256) void vq_rescue_merge(
        const float* __restrict__ x,
        const float* __restrict__ embT,
        const float* __restrict__ Anorm,
        const float* __restrict__ Sabs,
        const float* __restrict__ enorm,
        const float* __restrict__ gmin16,
        float* __restrict__ out,
        double* __restrict__ lossacc) {
    const int tid = threadIdx.x, l = tid & 63, w = tid >> 6;
    const int row = blockIdx.x * 4 + w;
    float gv = gmin16[(size_t)row * 64 + l];
    float gm = gv;
    #pragma unroll
    for (int m = 1; m < 64; m <<= 1) gm = fminf(gm, __shfl_xor(gm, m));
    // margin identical to the r4 PASSING run (sound: 2*per-code bf16 bound)
    const float margin = fmaf(Sabs[row] * 0.05f, 0.017f, 0.002f);
    unsigned long long mask = __ballot(gv <= gm + margin);

    const float A = Anorm[row];
    const float4* __restrict__ xr = reinterpret_cast<const float4*>(x + (size_t)row * D);
    const int p   = l >> 4;    // up to 4 groups per pass, one per lane-group
    const int sub = l & 15;
    float bestd = 1e30f; int besti = 0x7fffffff;

    while (mask) {
        unsigned long long m = mask;          // p-th set bit (mask wave-uniform)
        if (p > 0) m &= m - 1;
        if (p > 1 && m) m &= m - 1;
        if (p > 2 && m) m &= m - 1;
        const int gp = m ? __builtin_ctzll(m) : __builtin_ctzll(mask); // idle->dup g0
        #pragma unroll
        for (int i = 0; i < 4; ++i) mask &= mask - 1;   // strip <=4 bits (0-safe)

        const int k = gp * 16 + sub;
        const float4* __restrict__ er =
            reinterpret_cast<const float4*>(embT + (size_t)k * D);
        // EXACT reference chain: sequential-d fp32 fmaf, d = 0..255
        float c = 0.f;
        #pragma unroll 8
        for (int d4 = 0; d4 < 64; ++d4) {
            float4 e  = er[d4];     // per-lane contiguous stream
            float4 xv = xr[d4];     // wave-uniform broadcast
            c = fmaf(xv.x, e.x, c);
            c = fmaf(xv.y, e.y, c);
            c = fmaf(xv.z, e.z, c);
            c = fmaf(xv.w, e.w, c);
        }
        float dist = __fadd_rn(__fsub_rn(A, 2.0f * c), enorm[k]); // fl(fl(A-2B)+C)
        if (dist < bestd || (dist == bestd && k < besti)) { bestd = dist; besti = k; }
    }
    #pragma unroll
    for (int m = 1; m < 64; m <<= 1) {        // lexicographic (dist, idx) min
        float od = __shfl_xor(bestd, m);
        int   oi = __shfl_xor(besti, m);
        if (od < bestd || (od == bestd && oi < besti)) { bestd = od; besti = oi; }
    }
    besti = __shfl(besti, 0);

    // fused merge: gather winning code, write out row, accumulate loss
    const float4* __restrict__ eb =
        reinterpret_cast<const float4*>(embT + (size_t)besti * D);
    float4 xv = xr[l];
    float4 q  = eb[l];
    reinterpret_cast<float4*>(out + (size_t)row * D)[l] = q;  // exact pass-through
    double lsum = 0.0, dxx;
    dxx = (double)q.x - (double)xv.x; lsum = fma(dxx, dxx, lsum);
    dxx = (double)q.y - (double)xv.y; lsum = fma(dxx, dxx, lsum);
    dxx = (double)q.z - (double)xv.z; lsum = fma(dxx, dxx, lsum);
    dxx = (double)q.w - (double)xv.w; lsum = fma(dxx, dxx, lsum);
    for (int off = 32; off > 0; off >>= 1) lsum += __shfl_down(lsum, off);
    if (l == 0) atomicAdd(lossacc, lsum);
}

__global__ void vq_loss(const double* __restrict__ lossacc, float* __restrict__ out_loss) {
    if (threadIdx.x == 0 && blockIdx.x == 0) {
        out_loss[0] = (float)(1.25 * (lossacc[0] / (double)((size_t)N_PTS * D)));
    }
}

extern "C" void kernel_launch(void* const* d_in, const int* in_sizes, int n_in,
                              void* d_out, int out_size, void* d_ws, size_t ws_size,
                              hipStream_t stream) {
    const float* x   = (const float*)d_in[0];
    const float* emb = (const float*)d_in[1];
    float* out = (float*)d_out;
    char* ws = (char*)d_ws;

    float*  enorm   = (float*)(ws);
    double* lossacc = (double*)(ws + 8192);
    float*  Anorm   = (float*)(ws + 16384);
    float*  Sabs    = (float*)(ws + 147456);
    unsigned short* ehT = (unsigned short*)(ws + 409600);
    float*  embT    = (float*)(ws + 933888);
    float*  gmin16  = (float*)(ws + 1982464);           // 8 MB, ends ~10.4 MB
    unsigned short* xh = (unsigned short*)out;          // d_out scratch: screen
                                                        // input, overwritten after
    hipMemsetAsync(lossacc, 0, sizeof(double), stream);
    vq_prepx<<<N_PTS * 2 / 256, 256, 0, stream>>>(x, Anorm, Sabs, xh);
    vq_enorm<<<K / 256, 256, 0, stream>>>(emb, enorm);
    vq_prepe<<<64, 256, 0, stream>>>(emb, embT, ehT);
    vq_screen<<<(N_PTS / 128) * (K / 128), 256, 0, stream>>>(xh, ehT, Anorm, enorm, gmin16);
    vq_rescue_merge<<<N_PTS / 4, 256, 0, stream>>>(x, embT, Anorm, Sabs, enorm,
                                                   gmin16, out, lossacc);
    vq_loss<<<1, 64, 0, stream>>>(lossacc, out + (size_t)N_PTS * D);
}

// Round 6
// 581.080 us; speedup vs baseline: 1.0329x; 1.0329x over previous
//
#include <hip/hip_runtime.h>

// VQ-VAE VectorQuantizer: x[32768,256] fp32, emb[256,1024] fp32.
// Round 6: screen unchanged (r4/r5-verified). Rescue re-addressed:
//   - emb[d*K+k] row-major loads: <=4 cache lines per wave instruction
//     (lane-groups across k; idle groups dup group0 -> same-line coalesce)
//   - x row staged in LDS per wave (broadcast reads)
//   - merge stays fused; prep kernels consolidated into one launch.
// All rounding/flag/tie-break semantics bit-identical to the r4 passing run.

#define D 256
#define K 1024
#define N_PTS 32768

typedef __attribute__((ext_vector_type(8))) short short8v;   // 8 bf16 (4 VGPR)
typedef __attribute__((ext_vector_type(4))) float f32x4;     // MFMA acc
typedef __attribute__((ext_vector_type(4))) unsigned short us4v;

__device__ __forceinline__ unsigned short bf16rne(float f) {
    unsigned u = __float_as_uint(f);                 // finite data, no NaN
    return (unsigned short)((u + 0x7FFFu + ((u >> 16) & 1u)) >> 16);
}

// ws layout (bytes):
//   0        float  enorm[1024]        4 KB   (numpy-sequential fp32 ||e||^2)
//   8192     double lossacc            8 B
//   16384    float  Anorm[32768]       128 KB (numpy pairwise ||x||^2)
//   147456   float  Sabs[32768]        128 KB (sum|x| for margin bound)
//   409600   ushort ehT[1024][256]     512 KB (bf16, code-major)
//   933888   float  embT[1024][256]    1 MB   (f32, code-major, merge gather)
//   1982464  float  gmin16[32768][64]  8 MB
// xh bf16 [32768][256] (16 MB) lives in d_out scratch (consumed by screen,
// overwritten by the fused rescue/merge afterwards).

// ---- consolidated prep: blocks 0-255 prepx, 256-259 enorm, 260-323 prepe ----
__global__ __launch_bounds__(256) void vq_prep(const float* __restrict__ x,
                                               const float* __restrict__ emb,
                                               float* __restrict__ Anorm,
                                               float* __restrict__ Sabs,
                                               unsigned short* __restrict__ xh,
                                               float* __restrict__ enorm,
                                               float* __restrict__ embT,
                                               unsigned short* __restrict__ ehT) {
    __shared__ float tile[64][68];
    const int b = blockIdx.x;
    const int tid = threadIdx.x;

    if (b < 256) {
        // ---- prepx: Anorm (numpy pairwise), Sabs, xh bf16 ----
        const int gt = b * 256 + tid;
        const int n  = gt >> 1;
        const int h  = gt & 1;
        const float4* __restrict__ xr =
            reinterpret_cast<const float4*>(x + (size_t)n * D) + h * 32;
        unsigned short* __restrict__ xo = xh + (size_t)n * D + h * 128;

        float r[8], sab;
        float4 u = xr[0], v = xr[1];
        {
            short8v p;
            p[0]=(short)bf16rne(u.x); p[1]=(short)bf16rne(u.y);
            p[2]=(short)bf16rne(u.z); p[3]=(short)bf16rne(u.w);
            p[4]=(short)bf16rne(v.x); p[5]=(short)bf16rne(v.y);
            p[6]=(short)bf16rne(v.z); p[7]=(short)bf16rne(v.w);
            *reinterpret_cast<short8v*>(xo) = p;
        }
        r[0]=__fmul_rn(u.x,u.x); r[1]=__fmul_rn(u.y,u.y);
        r[2]=__fmul_rn(u.z,u.z); r[3]=__fmul_rn(u.w,u.w);
        r[4]=__fmul_rn(v.x,v.x); r[5]=__fmul_rn(v.y,v.y);
        r[6]=__fmul_rn(v.z,v.z); r[7]=__fmul_rn(v.w,v.w);
        sab = fabsf(u.x)+fabsf(u.y)+fabsf(u.z)+fabsf(u.w)
            + fabsf(v.x)+fabsf(v.y)+fabsf(v.z)+fabsf(v.w);
        #pragma unroll
        for (int i = 1; i < 16; ++i) {
            u = xr[2*i]; v = xr[2*i+1];
            short8v p;
            p[0]=(short)bf16rne(u.x); p[1]=(short)bf16rne(u.y);
            p[2]=(short)bf16rne(u.z); p[3]=(short)bf16rne(u.w);
            p[4]=(short)bf16rne(v.x); p[5]=(short)bf16rne(v.y);
            p[6]=(short)bf16rne(v.z); p[7]=(short)bf16rne(v.w);
            *reinterpret_cast<short8v*>(xo + i * 8) = p;
            r[0]=__fadd_rn(r[0],__fmul_rn(u.x,u.x));
            r[1]=__fadd_rn(r[1],__fmul_rn(u.y,u.y));
            r[2]=__fadd_rn(r[2],__fmul_rn(u.z,u.z));
            r[3]=__fadd_rn(r[3],__fmul_rn(u.w,u.w));
            r[4]=__fadd_rn(r[4],__fmul_rn(v.x,v.x));
            r[5]=__fadd_rn(r[5],__fmul_rn(v.y,v.y));
            r[6]=__fadd_rn(r[6],__fmul_rn(v.z,v.z));
            r[7]=__fadd_rn(r[7],__fmul_rn(v.w,v.w));
            sab += fabsf(u.x)+fabsf(u.y)+fabsf(u.z)+fabsf(u.w)
                 + fabsf(v.x)+fabsf(v.y)+fabsf(v.z)+fabsf(v.w);
        }
        float ah = __fadd_rn(__fadd_rn(__fadd_rn(r[0],r[1]),__fadd_rn(r[2],r[3])),
                             __fadd_rn(__fadd_rn(r[4],r[5]),__fadd_rn(r[6],r[7])));
        float oh = __shfl_xor(ah, 1);
        float os = __shfl_xor(sab, 1);
        if (h == 0) {
            Anorm[n] = __fadd_rn(ah, oh);   // fl(half0 + half1), numpy order
            Sabs[n]  = sab + os;
        }
    } else if (b < 260) {
        // ---- enorm: numpy axis-0 sequential fp32 sum of squares ----
        int k = (b - 256) * 256 + tid;
        float c = 0.0f;
        for (int d = 0; d < D; ++d) {
            float e = emb[d * K + k];
            c = __fadd_rn(c, __fmul_rn(e, e));
        }
        enorm[k] = c;
    } else {
        // ---- prepe: embT f32 + ehT bf16 (code-major transposes) ----
        const int bb = b - 260;
        const int bk = bb >> 2, bd = bb & 3;
        const int k0 = bk * 64, d0 = bd * 64;
        #pragma unroll
        for (int s = 0; s < 4; ++s) {
            int li = s * 256 + tid;
            int dd = li >> 4, kq = li & 15;
            float4 v = *reinterpret_cast<const float4*>(
                &emb[(size_t)(d0 + dd) * K + k0 + kq * 4]);
            tile[dd][kq*4+0]=v.x; tile[dd][kq*4+1]=v.y;
            tile[dd][kq*4+2]=v.z; tile[dd][kq*4+3]=v.w;
        }
        __syncthreads();
        #pragma unroll
        for (int s = 0; s < 4; ++s) {
            int li = s * 256 + tid;
            int kk = li >> 4, dq = li & 15;
            float4 v;
            v.x = tile[dq*4+0][kk]; v.y = tile[dq*4+1][kk];
            v.z = tile[dq*4+2][kk]; v.w = tile[dq*4+3][kk];
            *reinterpret_cast<float4*>(&embT[(size_t)(k0+kk)*D + d0 + dq*4]) = v;
            us4v hq;
            hq[0]=bf16rne(v.x); hq[1]=bf16rne(v.y);
            hq[2]=bf16rne(v.z); hq[3]=bf16rne(v.w);
            *reinterpret_cast<us4v*>(&ehT[(size_t)(k0+kk)*D + d0 + dq*4]) = hq;
        }
    }
}

// ---- bf16 MFMA screen: 128x128 tile, 4 waves (2x2), 16x16x32 MFMA ----
#define LDSTR 40   // ushorts per LDS row (80B): 16B-aligned, 2-way banks (free)

__global__ __launch_bounds__(256) void vq_screen(const unsigned short* __restrict__ xh,
                                                 const unsigned short* __restrict__ ehT,
                                                 const float* __restrict__ Anorm,
                                                 const float* __restrict__ enorm,
                                                 float* __restrict__ gmin16) {
    __shared__ unsigned short a_lds[128 * LDSTR];
    __shared__ unsigned short b_lds[128 * LDSTR];
    const int tid = threadIdx.x;
    const int l = tid & 63, wid = tid >> 6;
    const int wr = wid >> 1, wc = wid & 1;        // wave tile 64x64
    const int rt = blockIdx.x >> 3, cc = blockIdx.x & 7;
    const int n0 = rt * 128, c0 = cc * 128;
    const int g = l >> 4, cl = l & 15;

    f32x4 acc[4][4];
    #pragma unroll
    for (int mf = 0; mf < 4; ++mf)
        #pragma unroll
        for (int nf = 0; nf < 4; ++nf)
            acc[mf][nf] = (f32x4){0.f, 0.f, 0.f, 0.f};

    const int srow = tid >> 1, sq = (tid & 1) * 2;   // staging: 2x16B per thread
    for (int s = 0; s < 8; ++s) {                    // K = 8 steps of 32
        __syncthreads();
        {
            const short8v* ga = reinterpret_cast<const short8v*>(
                xh + (size_t)(n0 + srow) * D + s * 32 + sq * 8);
            short8v a0 = ga[0], a1 = ga[1];
            *reinterpret_cast<short8v*>(&a_lds[srow * LDSTR + sq * 8])     = a0;
            *reinterpret_cast<short8v*>(&a_lds[srow * LDSTR + sq * 8 + 8]) = a1;
            const short8v* gb = reinterpret_cast<const short8v*>(
                ehT + (size_t)(c0 + srow) * D + s * 32 + sq * 8);
            short8v b0 = gb[0], b1 = gb[1];
            *reinterpret_cast<short8v*>(&b_lds[srow * LDSTR + sq * 8])     = b0;
            *reinterpret_cast<short8v*>(&b_lds[srow * LDSTR + sq * 8 + 8]) = b1;
        }
        __syncthreads();
        short8v af[4], bf[4];
        #pragma unroll
        for (int mf = 0; mf < 4; ++mf)
            af[mf] = *reinterpret_cast<const short8v*>(
                &a_lds[(wr * 64 + mf * 16 + cl) * LDSTR + g * 8]);
        #pragma unroll
        for (int nf = 0; nf < 4; ++nf)
            bf[nf] = *reinterpret_cast<const short8v*>(
                &b_lds[(wc * 64 + nf * 16 + cl) * LDSTR + g * 8]);
        #pragma unroll
        for (int mf = 0; mf < 4; ++mf)
            #pragma unroll
            for (int nf = 0; nf < 4; ++nf)
                acc[mf][nf] = __builtin_amdgcn_mfma_f32_16x16x32_bf16(
                    af[mf], bf[nf], acc[mf][nf], 0, 0, 0);
    }

    // epilogue: screen dist + per-row 16-code group mins
    #pragma unroll
    for (int mf = 0; mf < 4; ++mf) {
        #pragma unroll
        for (int nf = 0; nf < 4; ++nf) {
            f32x4 a = acc[mf][nf];
            const int cg = c0 + wc * 64 + nf * 16 + cl;
            const float C = enorm[cg];
            #pragma unroll
            for (int r = 0; r < 4; ++r) {
                const int ng = n0 + wr * 64 + mf * 16 + g * 4 + r;
                float dist = Anorm[ng] - 2.0f * a[r] + C;
                #pragma unroll
                for (int m = 1; m <= 8; m <<= 1)
                    dist = fminf(dist, __shfl_xor(dist, m));
                if (cl == 0)
                    gmin16[(size_t)ng * 64 + cc * 8 + wc * 4 + nf] = dist;
            }
        }
    }
}

// ---- fused exact rescue + gather/out/loss: one wave per row ----
__global__ __launch_bounds__(256) void vq_rescue_merge(
        const float* __restrict__ x,
        const float* __restrict__ emb,
        const float* __restrict__ embT,
        const float* __restrict__ Anorm,
        const float* __restrict__ Sabs,
        const float* __restrict__ enorm,
        const float* __restrict__ gmin16,
        float* __restrict__ out,
        double* __restrict__ lossacc) {
    __shared__ float xs[4][256];   // one x row per wave, broadcast-read
    const int tid = threadIdx.x, l = tid & 63, w = tid >> 6;
    const int row = blockIdx.x * 4 + w;

    const float4 xv4 = reinterpret_cast<const float4*>(x + (size_t)row * D)[l];
    *reinterpret_cast<float4*>(&xs[w][l * 4]) = xv4;

    float gv = gmin16[(size_t)row * 64 + l];
    float gm = gv;
    #pragma unroll
    for (int m = 1; m < 64; m <<= 1) gm = fminf(gm, __shfl_xor(gm, m));
    // margin identical to the r4 PASSING run (sound: 2*per-code bf16 bound)
    const float margin = fmaf(Sabs[row] * 0.05f, 0.017f, 0.002f);
    unsigned long long mask = __ballot(gv <= gm + margin);

    __syncthreads();   // xs visible (also covers cross-wave ordering; cheap)

    const float A = Anorm[row];
    const int p   = l >> 4;    // up to 4 groups per pass, one per lane-group
    const int sub = l & 15;
    float bestd = 1e30f; int besti = 0x7fffffff;

    while (mask) {
        unsigned long long m = mask;          // p-th set bit (mask wave-uniform)
        if (p > 0) m &= m - 1;
        if (p > 1 && m) m &= m - 1;
        if (p > 2 && m) m &= m - 1;
        const int gp = m ? __builtin_ctzll(m) : __builtin_ctzll(mask); // idle->dup g0
        #pragma unroll
        for (int i = 0; i < 4; ++i) mask &= mask - 1;   // strip <=4 bits (0-safe)

        const int k = gp * 16 + sub;
        // EXACT reference chain: sequential-d fp32 fmaf. Loads emb[d*K+k]:
        // 16 consecutive k per lane-group = 1 line; <=4 lines per instruction
        // (dup lane-groups hit group0's line -> coalesced).
        const float* __restrict__ ek = emb + k;
        float c = 0.f;
        #pragma unroll 16
        for (int d = 0; d < D; ++d)
            c = fmaf(xs[w][d], ek[(size_t)d * K], c);
        float dist = __fadd_rn(__fsub_rn(A, 2.0f * c), enorm[k]); // fl(fl(A-2B)+C)
        if (dist < bestd || (dist == bestd && k < besti)) { bestd = dist; besti = k; }
    }
    #pragma unroll
    for (int m = 1; m < 64; m <<= 1) {        // lexicographic (dist, idx) min
        float od = __shfl_xor(bestd, m);
        int   oi = __shfl_xor(besti, m);
        if (od < bestd || (od == bestd && oi < besti)) { bestd = od; besti = oi; }
    }
    besti = __shfl(besti, 0);

    // fused merge: gather winning code (code-major, coalesced), write, loss
    const float4 q = reinterpret_cast<const float4*>(embT + (size_t)besti * D)[l];
    reinterpret_cast<float4*>(out + (size_t)row * D)[l] = q;  // exact pass-through
    double lsum = 0.0, dxx;
    dxx = (double)q.x - (double)xv4.x; lsum = fma(dxx, dxx, lsum);
    dxx = (double)q.y - (double)xv4.y; lsum = fma(dxx, dxx, lsum);
    dxx = (double)q.z - (double)xv4.z; lsum = fma(dxx, dxx, lsum);
    dxx = (double)q.w - (double)xv4.w; lsum = fma(dxx, dxx, lsum);
    for (int off = 32; off > 0; off >>= 1) lsum += __shfl_down(lsum, off);
    if (l == 0) atomicAdd(lossacc, lsum);
}

__global__ void vq_loss(const double* __restrict__ lossacc, float* __restrict__ out_loss) {
    if (threadIdx.x == 0 && blockIdx.x == 0) {
        out_loss[0] = (float)(1.25 * (lossacc[0] / (double)((size_t)N_PTS * D)));
    }
}

extern "C" void kernel_launch(void* const* d_in, const int* in_sizes, int n_in,
                              void* d_out, int out_size, void* d_ws, size_t ws_size,
                              hipStream_t stream) {
    const float* x   = (const float*)d_in[0];
    const float* emb = (const float*)d_in[1];
    float* out = (float*)d_out;
    char* ws = (char*)d_ws;

    float*  enorm   = (float*)(ws);
    double* lossacc = (double*)(ws + 8192);
    float*  Anorm   = (float*)(ws + 16384);
    float*  Sabs    = (float*)(ws + 147456);
    unsigned short* ehT = (unsigned short*)(ws + 409600);
    float*  embT    = (float*)(ws + 933888);
    float*  gmin16  = (float*)(ws + 1982464);           // 8 MB, ends ~10.4 MB
    unsigned short* xh = (unsigned short*)out;          // d_out scratch: screen
                                                        // input, overwritten after
    hipMemsetAsync(lossacc, 0, sizeof(double), stream);
    vq_prep<<<256 + 4 + 64, 256, 0, stream>>>(x, emb, Anorm, Sabs, xh,
                                              enorm, embT, ehT);
    vq_screen<<<(N_PTS / 128) * (K / 128), 256, 0, stream>>>(xh, ehT, Anorm, enorm, gmin16);
    vq_rescue_merge<<<N_PTS / 4, 256, 0, stream>>>(x, emb, embT, Anorm, Sabs,
                                                   enorm, gmin16, out, lossacc);
    vq_loss<<<1, 64, 0, stream>>>(lossacc, out + (size_t)N_PTS * D);
}